// Round 3
// baseline (586.855 us; speedup 1.0000x reference)
//
#include <hip/hip_runtime.h>

typedef unsigned short u16;
typedef unsigned int u32;
typedef __attribute__((ext_vector_type(8))) short short8;
typedef __attribute__((ext_vector_type(4))) float f32x4;

#define NN 50000
#define EE 800000

__device__ __forceinline__ float b2f(u16 u){ union{float f;u32 i;}x; x.i=((u32)u)<<16; return x.f; }
__device__ __forceinline__ u16 f2b(float f){ union{float f;u32 i;}x; x.f=f; u32 i=x.i; return (u16)((i + 0x7fffu + ((i>>16)&1u))>>16); }

// ---------- converts ----------
__global__ void k_f2b4(const float* __restrict__ x, u16* __restrict__ y, int n4){
  int i = blockIdx.x*256 + threadIdx.x;
  if (i >= n4) return;
  float4 v = ((const float4*)x)[i];
  ushort4 o; o.x=f2b(v.x); o.y=f2b(v.y); o.z=f2b(v.z); o.w=f2b(v.w);
  ((ushort4*)y)[i]=o;
}

// concat [rWo | Wo] -> Bcat[256][320] bf16
__global__ void k_catWo(const float* __restrict__ rWo, const float* __restrict__ Wo, u16* __restrict__ Bcat){
  int i = blockIdx.x*256 + threadIdx.x;
  if (i >= 256*320) return;
  int k = i/320, c = i%320;
  float v = (c < 160) ? rWo[k*160 + c] : Wo[k*160 + (c-160)];
  Bcat[i] = f2b(v);
}

// ---------- CSR build ----------
__global__ void k_count(const int* __restrict__ dst, int* __restrict__ cnt){
  int i = blockIdx.x*256+threadIdx.x; if (i<EE) atomicAdd(&cnt[dst[i]],1);
}

__global__ void k_scan_blocks(const int* __restrict__ cnt, int* __restrict__ off, int* __restrict__ part, int n){
  __shared__ int ts[256];
  int t = threadIdx.x; int base = blockIdx.x*1024 + t*4;
  int c0 = (base+0<n)?cnt[base+0]:0;
  int c1 = (base+1<n)?cnt[base+1]:0;
  int c2 = (base+2<n)?cnt[base+2]:0;
  int c3 = (base+3<n)?cnt[base+3]:0;
  int s = c0+c1+c2+c3;
  ts[t]=s; __syncthreads();
  for (int d=1; d<256; d<<=1){ int v=(t>=d)?ts[t-d]:0; __syncthreads(); ts[t]+=v; __syncthreads(); }
  int ex = ts[t]-s;
  if (t==255) part[blockIdx.x]=ts[255];
  if (base+0<n) off[base+0]=ex; ex+=c0;
  if (base+1<n) off[base+1]=ex; ex+=c1;
  if (base+2<n) off[base+2]=ex; ex+=c2;
  if (base+3<n) off[base+3]=ex;
}

__global__ void k_scan_part(int* part, int nb){
  if (threadIdx.x==0 && blockIdx.x==0){ int run=0; for(int i=0;i<nb;++i){ int v=part[i]; part[i]=run; run+=v; } }
}

__global__ void k_addback(int* off, const int* __restrict__ part, int n){
  int base = blockIdx.x*1024 + threadIdx.x*4; int p = part[blockIdx.x];
  #pragma unroll
  for (int j=0;j<4;++j) if (base+j<n) off[base+j]+=p;
}

__global__ void k_copy(const int* __restrict__ a, int* __restrict__ b, int n){
  int i=blockIdx.x*256+threadIdx.x; if(i<n) b[i]=a[i];
}

__global__ void k_scatter(const int* __restrict__ src, const int* __restrict__ dst, int* __restrict__ cur,
                          int* __restrict__ srcs){
  int i = blockIdx.x*256+threadIdx.x; if (i>=EE) return;
  int d = dst[i]; int p = atomicAdd(&cur[d],1);
  srcs[p]=src[i];
}

// ---------- GEMM: C[M,N] = A[M,256](bf16) @ B[256,N](bf16), f32 acc, BN=64 ----------
template<int MODE>
__global__ __launch_bounds__(256) void k_gemm(const u16* __restrict__ A, const u16* __restrict__ B,
                                              void* __restrict__ C0, void* __restrict__ C1,
                                              int M, int N){
  __shared__ u16 Bt[64][266];   // Bt[c][k]
  const int tid = threadIdx.x;
  const int n0 = blockIdx.y * 64;
  const int row0 = blockIdx.x * 256;
  #pragma unroll
  for (int r=0; r<32; ++r){
    int lin = r*256 + tid;          // 0..8191
    int kk = lin >> 5;              // 0..255
    int cp = (lin & 31) << 1;       // 0,2,..,62
    ushort2 v = *(const ushort2*)(B + (size_t)kk*N + n0 + cp);
    Bt[cp][kk] = v.x; Bt[cp+1][kk] = v.y;
  }
  __syncthreads();
  const int w = tid >> 6, l = tid & 63;
  const int lr = l & 15, lq = l >> 4;
  const int wrow = row0 + w*64;
  f32x4 acc[4][4];
  #pragma unroll
  for (int fr=0; fr<4; ++fr)
    #pragma unroll
    for (int j=0; j<4; ++j) acc[fr][j] = (f32x4)0.0f;
  #pragma unroll
  for (int k0 = 0; k0 < 256; k0 += 32){
    short8 a[4], b[4];
    #pragma unroll
    for (int fr=0; fr<4; ++fr){
      int r = wrow + fr*16 + lr; r = r < M ? r : M-1;
      a[fr] = *(const short8*)(A + (size_t)r*256 + k0 + lq*8);
    }
    #pragma unroll
    for (int j=0; j<4; ++j)
      b[j] = *(const short8*)(&Bt[j*16 + lr][k0 + lq*8]);
    #pragma unroll
    for (int fr=0; fr<4; ++fr)
      #pragma unroll
      for (int j=0; j<4; ++j)
        acc[fr][j] = __builtin_amdgcn_mfma_f32_16x16x32_bf16(a[fr], b[j], acc[fr][j], 0, 0, 0);
  }
  #pragma unroll
  for (int fr=0; fr<4; ++fr)
    #pragma unroll
    for (int j=0; j<4; ++j)
      #pragma unroll
      for (int q=0; q<4; ++q){
        int r = wrow + fr*16 + lq*4 + q;
        if (r < M){
          int c = n0 + j*16 + lr;
          float v = acc[fr][j][q];
          if constexpr (MODE == 0)      ((float*)C0)[(size_t)r*N + c] = v;
          else if constexpr (MODE == 1) ((u16*)C0)[(size_t)r*N + c] = f2b(v);
          else {
            if (c < 160) ((u16*)C0)[(size_t)r*160 + c]       = f2b(v);
            else         ((u16*)C1)[(size_t)r*160 + (c-160)] = f2b(v);
          }
        }
      }
}

// ---------- el/er for HD=256 (Dh=64): wave per node, vectorized ----------
__global__ void k_eler256(const u16* __restrict__ feat, const float* __restrict__ al, const float* __restrict__ ar,
                          float* __restrict__ el, float* __restrict__ er){
  int t = blockIdx.x*256 + threadIdx.x;
  int n = t >> 6, l = t & 63;
  if (n >= NN) return;
  float4 a4 = ((const float4*)al)[l];
  float4 r4 = ((const float4*)ar)[l];
  ushort4 f = *(const ushort4*)(feat + (size_t)n*256 + l*4);
  float f0=b2f(f.x), f1=b2f(f.y), f2=b2f(f.z), f3=b2f(f.w);
  float accl = f0*a4.x + f1*a4.y + f2*a4.z + f3*a4.w;
  float accr = f0*r4.x + f1*r4.y + f2*r4.z + f3*r4.w;
  #pragma unroll
  for (int m = 8; m >= 1; m >>= 1){ accl += __shfl_xor(accl, m, 64); accr += __shfl_xor(accr, m, 64); }
  int h = l >> 4;
  if ((l & 15) == 0){ el[n*4+h] = accl; er[n*4+h] = accr; }
}

// ---------- generic el/er (output layer: Dh=40, HD=160) ----------
__global__ void k_eler(const u16* __restrict__ feat, const float* __restrict__ al, const float* __restrict__ ar,
                       float* __restrict__ el, float* __restrict__ er, int Dh, int HD){
  int t = blockIdx.x*256 + threadIdx.x;
  int n = t >> 6; int l = t & 63;
  if (n >= NN) return;
  int h = l >> 4, s = l & 15;
  const u16* fr = feat + (size_t)n*HD + h*Dh;
  const float* alh = al + h*Dh; const float* arh = ar + h*Dh;
  float accl = 0.f, accr = 0.f;
  for (int d = s; d < Dh; d += 16){ float f = b2f(fr[d]); accl += f*alh[d]; accr += f*arh[d]; }
  #pragma unroll
  for (int m = 8; m >= 1; m >>= 1){ accl += __shfl_xor(accl, m, 64); accr += __shfl_xor(accr, m, 64); }
  if (s == 0){ el[n*4+h] = accl; er[n*4+h] = accr; }
}

// ---------- fused edge-score + per-node softmax (pass1 gather+store, pass2 linear) ----------
__global__ void k_soft(const float* __restrict__ el, const float* __restrict__ er,
                       const int* __restrict__ srcs, const int* __restrict__ off,
                       float* __restrict__ es, float* __restrict__ recs){
  int n = blockIdx.x*256 + threadIdx.x; if (n >= NN) return;
  int o0 = off[n], o1 = off[n+1];
  float4 e4 = ((const float4*)er)[n];
  float4 m; m.x=m.y=m.z=m.w=-1e30f;
  for (int i=o0;i<o1;++i){
    float4 a = ((const float4*)el)[srcs[i]];
    float4 v;
    v.x=a.x+e4.x; v.x = v.x>=0.f?v.x:0.2f*v.x;
    v.y=a.y+e4.y; v.y = v.y>=0.f?v.y:0.2f*v.y;
    v.z=a.z+e4.z; v.z = v.z>=0.f?v.z:0.2f*v.z;
    v.w=a.w+e4.w; v.w = v.w>=0.f?v.w:0.2f*v.w;
    ((float4*)es)[i]=v;
    m.x=fmaxf(m.x,v.x); m.y=fmaxf(m.y,v.y); m.z=fmaxf(m.z,v.z); m.w=fmaxf(m.w,v.w);
  }
  float4 s; s.x=s.y=s.z=s.w=0.f;
  for (int i=o0;i<o1;++i){
    float4 v = ((const float4*)es)[i];
    v.x=__expf(v.x-m.x); v.y=__expf(v.y-m.y); v.z=__expf(v.z-m.z); v.w=__expf(v.w-m.w);
    ((float4*)es)[i]=v; s.x+=v.x; s.y+=v.y; s.z+=v.z; s.w+=v.w;
  }
  float4 r;
  r.x = s.x>0.f ? 1.f/s.x : 0.f;
  r.y = s.y>0.f ? 1.f/s.y : 0.f;
  r.z = s.z>0.f ? 1.f/s.z : 0.f;
  r.w = s.w>0.f ? 1.f/s.w : 0.f;
  ((float4*)recs)[n] = r;
}

// ---------- aggregation for D=64 layers: wave per node, half-wave edge pairs, 16B loads ----------
template<bool RES>
__global__ __launch_bounds__(256) void k_agg64(const u16* __restrict__ feat, const float* __restrict__ es,
    const float* __restrict__ recs, const int* __restrict__ off, const int* __restrict__ srcs,
    const u16* __restrict__ resid, float* __restrict__ outf, u16* __restrict__ outb){
  const int l = threadIdx.x & 63, w = threadIdx.x >> 6;
  const int n = blockIdx.x*4 + w;
  const int o0 = off[n], o1 = off[n+1];
  const int lh = l & 31;       // position within half-wave (covers full 512B row)
  const int half = l >> 5;     // which edge of the pair
  const int h = lh >> 3;       // head for this lane's 8 elements
  float a0=0.f,a1=0.f,a2=0.f,a3=0.f,a4=0.f,a5=0.f,a6=0.f,a7=0.f;
  int i = o0;
  for (; i + 8 <= o1; i += 8){
    #pragma unroll
    for (int u=0; u<4; ++u){
      int e = i + u*2 + half;
      int sv = srcs[e];
      float al = es[(size_t)e*4 + h];
      short8 f = *(const short8*)(feat + (size_t)sv*256 + lh*8);
      a0 += al*b2f((u16)f[0]); a1 += al*b2f((u16)f[1]);
      a2 += al*b2f((u16)f[2]); a3 += al*b2f((u16)f[3]);
      a4 += al*b2f((u16)f[4]); a5 += al*b2f((u16)f[5]);
      a6 += al*b2f((u16)f[6]); a7 += al*b2f((u16)f[7]);
    }
  }
  for (; i < o1; i += 2){
    int e = i + half;
    bool valid = e < o1;
    int ec = valid ? e : i;
    int sv = srcs[ec];
    float al = valid ? es[(size_t)ec*4 + h] : 0.f;
    short8 f = *(const short8*)(feat + (size_t)sv*256 + lh*8);
    a0 += al*b2f((u16)f[0]); a1 += al*b2f((u16)f[1]);
    a2 += al*b2f((u16)f[2]); a3 += al*b2f((u16)f[3]);
    a4 += al*b2f((u16)f[4]); a5 += al*b2f((u16)f[5]);
    a6 += al*b2f((u16)f[6]); a7 += al*b2f((u16)f[7]);
  }
  a0 += __shfl_xor(a0,32,64); a1 += __shfl_xor(a1,32,64);
  a2 += __shfl_xor(a2,32,64); a3 += __shfl_xor(a3,32,64);
  a4 += __shfl_xor(a4,32,64); a5 += __shfl_xor(a5,32,64);
  a6 += __shfl_xor(a6,32,64); a7 += __shfl_xor(a7,32,64);
  if (half == 0){
    float rc = recs[n*4+h];
    float v[8] = {a0*rc,a1*rc,a2*rc,a3*rc,a4*rc,a5*rc,a6*rc,a7*rc};
    if (RES){
      short8 r8 = *(const short8*)(resid + (size_t)n*256 + lh*8);
      #pragma unroll
      for (int j=0;j<8;++j) v[j] += b2f((u16)r8[j]);
    }
    #pragma unroll
    for (int j=0;j<8;++j) v[j] = v[j] > 0.f ? v[j] : expm1f(v[j]);
    if (outf){
      float4 q0; q0.x=v[0]; q0.y=v[1]; q0.z=v[2]; q0.w=v[3];
      float4 q1; q1.x=v[4]; q1.y=v[5]; q1.z=v[6]; q1.w=v[7];
      *(float4*)(outf + (size_t)n*256 + lh*8)     = q0;
      *(float4*)(outf + (size_t)n*256 + lh*8 + 4) = q1;
    }
    short8 ob;
    #pragma unroll
    for (int j=0;j<8;++j) ob[j] = (short)f2b(v[j]);
    *(short8*)(outb + (size_t)n*256 + lh*8) = ob;
  }
}

// ---------- output-layer aggregation: 8-edge groups, ushort4 slot loads ----------
__global__ __launch_bounds__(256) void k_agg_out(const u16* __restrict__ feat, const float* __restrict__ es,
    const float* __restrict__ recs, const int* __restrict__ off, const int* __restrict__ srcs,
    const u16* __restrict__ reso, float* __restrict__ logits){
  __shared__ f32x4 red[4][8][40];    // [wave][slot][q] = 20480 B
  __shared__ float fin[4][160];      // 2560 B
  const int l = threadIdx.x & 63, w = threadIdx.x >> 6;
  const int n = blockIdx.x*4 + w;
  const int o0 = off[n], o1 = off[n+1];
  int sA[5], qA[5], hA[5];
  #pragma unroll
  for (int r=0;r<5;++r){
    int p = r*64 + l;                 // 0..319 slots: 8 edges x 40 ushort4
    sA[r] = p/40; qA[r] = p%40; hA[r] = qA[r]/10;
  }
  f32x4 acc[5];
  #pragma unroll
  for (int r=0;r<5;++r) acc[r] = (f32x4)0.0f;
  for (int i0 = o0; i0 < o1; i0 += 8){
    int cnt = o1 - i0;
    #pragma unroll
    for (int r=0;r<5;++r){
      int s = sA[r];
      bool valid = s < cnt;
      int e = valid ? (i0 + s) : i0;
      int sv = srcs[e];
      float al = es[(size_t)e*4 + hA[r]];
      ushort4 f = *(const ushort4*)(feat + (size_t)sv*160 + qA[r]*4);
      if (!valid) al = 0.f;
      acc[r][0] += al*b2f(f.x); acc[r][1] += al*b2f(f.y);
      acc[r][2] += al*b2f(f.z); acc[r][3] += al*b2f(f.w);
    }
  }
  #pragma unroll
  for (int r=0;r<5;++r) red[w][sA[r]][qA[r]] = acc[r];
  __syncthreads();
  if (l < 40){
    f32x4 v = red[w][0][l];
    #pragma unroll
    for (int s=1;s<8;++s) v += red[w][s][l];
    float4 rc = ((const float4*)recs)[n];
    const float* rcp = (const float*)&rc;
    float rch = rcp[l/10];
    ushort4 rr = *(const ushort4*)(reso + (size_t)n*160 + l*4);
    fin[w][l*4+0] = v[0]*rch + b2f(rr.x);
    fin[w][l*4+1] = v[1]*rch + b2f(rr.y);
    fin[w][l*4+2] = v[2]*rch + b2f(rr.z);
    fin[w][l*4+3] = v[3]*rch + b2f(rr.w);
  }
  __syncthreads();
  if (l < 40) logits[(size_t)n*40 + l] = 0.25f*(fin[w][l]+fin[w][l+40]+fin[w][l+80]+fin[w][l+120]);
}

extern "C" void kernel_launch(void* const* d_in, const int* in_sizes, int n_in,
                              void* d_out, int out_size, void* d_ws, size_t ws_size,
                              hipStream_t stream){
  const float* inputs = (const float*)d_in[0];
  const int*   src    = (const int*)d_in[1];
  const int*   dst    = (const int*)d_in[2];
  const float* W0  = (const float*)d_in[3];
  const float* al0 = (const float*)d_in[4];
  const float* ar0 = (const float*)d_in[5];
  const float* W1  = (const float*)d_in[6];
  const float* al1 = (const float*)d_in[7];
  const float* ar1 = (const float*)d_in[8];
  const float* Wo  = (const float*)d_in[9];
  const float* alo = (const float*)d_in[10];
  const float* aro = (const float*)d_in[11];
  const float* rWo = (const float*)d_in[12];
  const float* fcW = (const float*)d_in[13];

  float* out = (float*)d_out;
  float* out_logits = out;                 // [50000,40]
  float* out_h      = out + 2000000;       // [50000,256]
  float* out_seq    = out + 14800000;      // [50000,64]

  char* ws = (char*)d_ws;
  size_t o = 0;
  auto alc = [&](size_t bytes){ size_t r = o; o += (bytes + 255) & ~(size_t)255; return r; };
  size_t oXb   = alc((size_t)NN*256*2);
  size_t oFA   = alc((size_t)NN*256*2);
  size_t oFB   = alc((size_t)NN*256*2);
  size_t oEs   = alc((size_t)EE*4*4);
  size_t oSrcs = alc((size_t)EE*4);
  size_t oOff  = alc((size_t)(NN+1)*4);
  size_t oCnt  = alc((size_t)(NN+1)*4);
  size_t oCur  = alc((size_t)NN*4);
  size_t oPart = alc(64*4);
  size_t oEl   = alc((size_t)NN*4*4);
  size_t oEr   = alc((size_t)NN*4*4);
  size_t oRecs = alc((size_t)NN*4*4);
  size_t oReso = alc((size_t)NN*160*2);
  size_t oW0b  = alc(256*256*2);
  size_t oW1b  = alc(256*256*2);
  size_t oWcat = alc(256*320*2);
  size_t oFcb  = alc(256*64*2);
  if (ws_size < o) return;

  u16* Xb   = (u16*)(ws + oXb);
  u16* fA   = (u16*)(ws + oFA);
  u16* fB   = (u16*)(ws + oFB);
  float* es = (float*)(ws + oEs);
  int* srcs = (int*)(ws + oSrcs);
  int* off  = (int*)(ws + oOff);
  int* cnt  = (int*)(ws + oCnt);
  int* cur  = (int*)(ws + oCur);
  int* part = (int*)(ws + oPart);
  float* el = (float*)(ws + oEl);
  float* er = (float*)(ws + oEr);
  float* recs = (float*)(ws + oRecs);
  u16* reso = (u16*)(ws + oReso);
  u16* W0b  = (u16*)(ws + oW0b);
  u16* W1b  = (u16*)(ws + oW1b);
  u16* Wcat = (u16*)(ws + oWcat);
  u16* fcb  = (u16*)(ws + oFcb);

  // ---- converts ----
  k_f2b4<<<(NN*256/4 + 255)/256, 256, 0, stream>>>(inputs, Xb, NN*256/4);
  k_f2b4<<<(65536/4 + 255)/256, 256, 0, stream>>>(W0, W0b, 65536/4);
  k_f2b4<<<(65536/4 + 255)/256, 256, 0, stream>>>(W1, W1b, 65536/4);
  k_catWo<<<(256*320 + 255)/256, 256, 0, stream>>>(rWo, Wo, Wcat);
  k_f2b4<<<(16384/4 + 255)/256, 256, 0, stream>>>(fcW, fcb, 16384/4);

  // ---- CSR ----
  hipMemsetAsync(cnt, 0, (size_t)(NN+1)*4, stream);
  k_count<<<(EE+255)/256, 256, 0, stream>>>(dst, cnt);
  const int NP1 = NN+1, NB = (NP1 + 1023)/1024;
  k_scan_blocks<<<NB, 256, 0, stream>>>(cnt, off, part, NP1);
  k_scan_part<<<1, 64, 0, stream>>>(part, NB);
  k_addback<<<NB, 256, 0, stream>>>(off, part, NP1);
  k_copy<<<(NN+255)/256, 256, 0, stream>>>(off, cur, NN);
  k_scatter<<<(EE+255)/256, 256, 0, stream>>>(src, dst, cur, srcs);

  dim3 gN256((NN+255)/256, 4), gN320((NN+255)/256, 5), gN64((NN+255)/256, 1);

  // ---- seq_fts = X @ fc_W (f32 out) ----
  k_gemm<0><<<gN64, 256, 0, stream>>>(Xb, fcb, out_seq, nullptr, NN, 64);

  // ---- layer 0 ----
  k_gemm<1><<<gN256, 256, 0, stream>>>(Xb, W0b, fA, nullptr, NN, 256);
  k_eler256<<<(NN*64 + 255)/256, 256, 0, stream>>>(fA, al0, ar0, el, er);
  k_soft<<<(NN+255)/256, 256, 0, stream>>>(el, er, srcs, off, es, recs);
  k_agg64<false><<<NN/4, 256, 0, stream>>>(fA, es, recs, off, srcs, nullptr, nullptr, fB);

  // ---- layer 1 ----
  k_gemm<1><<<gN256, 256, 0, stream>>>(fB, W1b, fA, nullptr, NN, 256);
  k_eler256<<<(NN*64 + 255)/256, 256, 0, stream>>>(fA, al1, ar1, el, er);
  k_soft<<<(NN+255)/256, 256, 0, stream>>>(el, er, srcs, off, es, recs);
  k_agg64<true><<<NN/4, 256, 0, stream>>>(fA, es, recs, off, srcs, fB, out_h, fB);

  // ---- output layer: fused [reso | feat] GEMM ----
  k_gemm<2><<<gN320, 256, 0, stream>>>(fB, Wcat, reso, fA, NN, 320);
  k_eler<<<(NN*64 + 255)/256, 256, 0, stream>>>(fA, alo, aro, el, er, 40, 160);
  k_soft<<<(NN+255)/256, 256, 0, stream>>>(el, er, srcs, off, es, recs);
  k_agg_out<<<NN/4, 256, 0, stream>>>(fA, es, recs, off, srcs, reso, out_logits);
}

// Round 4
// 506.954 us; speedup vs baseline: 1.1576x; 1.1576x over previous
//
#include <hip/hip_runtime.h>

typedef unsigned short u16;
typedef unsigned int u32;
typedef __attribute__((ext_vector_type(8))) short short8;
typedef __attribute__((ext_vector_type(4))) float f32x4;

#define NN 50000
#define EE 800000
#define EPAD (EE + 8*NN)   // max padded edges = 1,200,000

__device__ __forceinline__ float b2f(u16 u){ union{float f;u32 i;}x; x.i=((u32)u)<<16; return x.f; }
__device__ __forceinline__ u16 f2b(float f){ union{float f;u32 i;}x; x.f=f; u32 i=x.i; return (u16)((i + 0x7fffu + ((i>>16)&1u))>>16); }

// ---------- converts ----------
__global__ void k_f2b4(const float* __restrict__ x, u16* __restrict__ y, int n4){
  int i = blockIdx.x*256 + threadIdx.x;
  if (i >= n4) return;
  float4 v = ((const float4*)x)[i];
  ushort4 o; o.x=f2b(v.x); o.y=f2b(v.y); o.z=f2b(v.z); o.w=f2b(v.w);
  ((ushort4*)y)[i]=o;
}

// merged small-weight converts: W0(16384 quads) W1(16384) fcW(4096)
__global__ void k_wcvt(const float* __restrict__ W0, const float* __restrict__ W1, const float* __restrict__ fcW,
                       u16* __restrict__ W0b, u16* __restrict__ W1b, u16* __restrict__ fcb){
  int i = blockIdx.x*256 + threadIdx.x;
  const float* s; u16* d; int q;
  if (i < 16384){ s=W0; d=W0b; q=i; }
  else if (i < 32768){ s=W1; d=W1b; q=i-16384; }
  else if (i < 36864){ s=fcW; d=fcb; q=i-32768; }
  else return;
  float4 v = ((const float4*)s)[q];
  ushort4 o; o.x=f2b(v.x); o.y=f2b(v.y); o.z=f2b(v.z); o.w=f2b(v.w);
  ((ushort4*)d)[q]=o;
}

// concat [rWo | Wo] -> Bcat[256][320] bf16
__global__ void k_catWo(const float* __restrict__ rWo, const float* __restrict__ Wo, u16* __restrict__ Bcat){
  int i = blockIdx.x*256 + threadIdx.x;
  if (i >= 256*320) return;
  int k = i/320, c = i%320;
  float v = (c < 160) ? rWo[k*160 + c] : Wo[k*160 + (c-160)];
  Bcat[i] = f2b(v);
}

// ---------- CSR build (padded: each node segment rounded up to multiple of 8) ----------
__global__ void k_count(const int* __restrict__ dst, int* __restrict__ cnt){
  int i = blockIdx.x*256+threadIdx.x; if (i<EE) atomicAdd(&cnt[dst[i]],1);
}

__global__ void k_scan_blocks(const int* __restrict__ cnt, int* __restrict__ off, int* __restrict__ part, int n){
  __shared__ int ts[256];
  int t = threadIdx.x; int base = blockIdx.x*1024 + t*4;
  int c0 = (base+0<n)?((cnt[base+0]+7)&~7):0;
  int c1 = (base+1<n)?((cnt[base+1]+7)&~7):0;
  int c2 = (base+2<n)?((cnt[base+2]+7)&~7):0;
  int c3 = (base+3<n)?((cnt[base+3]+7)&~7):0;
  int s = c0+c1+c2+c3;
  ts[t]=s; __syncthreads();
  for (int d=1; d<256; d<<=1){ int v=(t>=d)?ts[t-d]:0; __syncthreads(); ts[t]+=v; __syncthreads(); }
  int ex = ts[t]-s;
  if (t==255) part[blockIdx.x]=ts[255];
  if (base+0<n) off[base+0]=ex; ex+=c0;
  if (base+1<n) off[base+1]=ex; ex+=c1;
  if (base+2<n) off[base+2]=ex; ex+=c2;
  if (base+3<n) off[base+3]=ex;
}

__global__ void k_scan_part(int* part, int nb){
  if (threadIdx.x==0 && blockIdx.x==0){ int run=0; for(int i=0;i<nb;++i){ int v=part[i]; part[i]=run; run+=v; } }
}

// addback and also initialize cur = off
__global__ void k_addback(int* off, int* cur, const int* __restrict__ part, int n){
  int base = blockIdx.x*1024 + threadIdx.x*4; int p = part[blockIdx.x];
  #pragma unroll
  for (int j=0;j<4;++j) if (base+j<n){ int v = off[base+j]+p; off[base+j]=v; if (base+j<NN) cur[base+j]=v; }
}

__global__ void k_scatter(const int* __restrict__ src, const int* __restrict__ dst, int* __restrict__ cur,
                          int* __restrict__ srcs){
  int i = blockIdx.x*256+threadIdx.x; if (i>=EE) return;
  int d = dst[i]; int p = atomicAdd(&cur[d],1);
  srcs[p]=src[i];
}

// ---------- GEMM: C[M,N] = A[M,256](bf16) @ B[256,N](bf16), f32 acc, BN=64 ----------
template<int MODE>
__global__ __launch_bounds__(256) void k_gemm(const u16* __restrict__ A, const u16* __restrict__ B,
                                              void* __restrict__ C0, void* __restrict__ C1,
                                              int M, int N){
  __shared__ u16 Bt[64][266];   // Bt[c][k]
  const int tid = threadIdx.x;
  const int n0 = blockIdx.y * 64;
  const int row0 = blockIdx.x * 256;
  #pragma unroll
  for (int r=0; r<32; ++r){
    int lin = r*256 + tid;          // 0..8191
    int kk = lin >> 5;              // 0..255
    int cp = (lin & 31) << 1;       // 0,2,..,62
    ushort2 v = *(const ushort2*)(B + (size_t)kk*N + n0 + cp);
    Bt[cp][kk] = v.x; Bt[cp+1][kk] = v.y;
  }
  __syncthreads();
  const int w = tid >> 6, l = tid & 63;
  const int lr = l & 15, lq = l >> 4;
  const int wrow = row0 + w*64;
  f32x4 acc[4][4];
  #pragma unroll
  for (int fr=0; fr<4; ++fr)
    #pragma unroll
    for (int j=0; j<4; ++j) acc[fr][j] = (f32x4)0.0f;
  #pragma unroll
  for (int k0 = 0; k0 < 256; k0 += 32){
    short8 a[4], b[4];
    #pragma unroll
    for (int fr=0; fr<4; ++fr){
      int r = wrow + fr*16 + lr; r = r < M ? r : M-1;
      a[fr] = *(const short8*)(A + (size_t)r*256 + k0 + lq*8);
    }
    #pragma unroll
    for (int j=0; j<4; ++j)
      b[j] = *(const short8*)(&Bt[j*16 + lr][k0 + lq*8]);
    #pragma unroll
    for (int fr=0; fr<4; ++fr)
      #pragma unroll
      for (int j=0; j<4; ++j)
        acc[fr][j] = __builtin_amdgcn_mfma_f32_16x16x32_bf16(a[fr], b[j], acc[fr][j], 0, 0, 0);
  }
  #pragma unroll
  for (int fr=0; fr<4; ++fr)
    #pragma unroll
    for (int j=0; j<4; ++j)
      #pragma unroll
      for (int q=0; q<4; ++q){
        int r = wrow + fr*16 + lq*4 + q;
        if (r < M){
          int c = n0 + j*16 + lr;
          float v = acc[fr][j][q];
          if constexpr (MODE == 0)      ((float*)C0)[(size_t)r*N + c] = v;
          else if constexpr (MODE == 1) ((u16*)C0)[(size_t)r*N + c] = f2b(v);
          else {
            if (c < 160) ((u16*)C0)[(size_t)r*160 + c]       = f2b(v);
            else         ((u16*)C1)[(size_t)r*160 + (c-160)] = f2b(v);
          }
        }
      }
}

// ---------- el/er for HD=256 (Dh=64): wave per node, vectorized ----------
__global__ void k_eler256(const u16* __restrict__ feat, const float* __restrict__ al, const float* __restrict__ ar,
                          float* __restrict__ el, float* __restrict__ er){
  int t = blockIdx.x*256 + threadIdx.x;
  int n = t >> 6, l = t & 63;
  if (n >= NN) return;
  float4 a4 = ((const float4*)al)[l];
  float4 r4 = ((const float4*)ar)[l];
  ushort4 f = *(const ushort4*)(feat + (size_t)n*256 + l*4);
  float f0=b2f(f.x), f1=b2f(f.y), f2=b2f(f.z), f3=b2f(f.w);
  float accl = f0*a4.x + f1*a4.y + f2*a4.z + f3*a4.w;
  float accr = f0*r4.x + f1*r4.y + f2*r4.z + f3*r4.w;
  #pragma unroll
  for (int m = 8; m >= 1; m >>= 1){ accl += __shfl_xor(accl, m, 64); accr += __shfl_xor(accr, m, 64); }
  int h = l >> 4;
  if ((l & 15) == 0){ el[n*4+h] = accl; er[n*4+h] = accr; }
}

// ---------- generic el/er (output layer: Dh=40, HD=160) ----------
__global__ void k_eler(const u16* __restrict__ feat, const float* __restrict__ al, const float* __restrict__ ar,
                       float* __restrict__ el, float* __restrict__ er, int Dh, int HD){
  int t = blockIdx.x*256 + threadIdx.x;
  int n = t >> 6; int l = t & 63;
  if (n >= NN) return;
  int h = l >> 4, s = l & 15;
  const u16* fr = feat + (size_t)n*HD + h*Dh;
  const float* alh = al + h*Dh; const float* arh = ar + h*Dh;
  float accl = 0.f, accr = 0.f;
  for (int d = s; d < Dh; d += 16){ float f = b2f(fr[d]); accl += f*alh[d]; accr += f*arh[d]; }
  #pragma unroll
  for (int m = 8; m >= 1; m >>= 1){ accl += __shfl_xor(accl, m, 64); accr += __shfl_xor(accr, m, 64); }
  if (s == 0){ el[n*4+h] = accl; er[n*4+h] = accr; }
}

// ---------- edge-parallel softmax: 16 lanes per node ----------
__global__ void k_soft(const float* __restrict__ el, const float* __restrict__ er,
                       const int* __restrict__ srcs, const int* __restrict__ off, const int* __restrict__ cnt,
                       float* __restrict__ es, float* __restrict__ recs){
  int t = blockIdx.x*256 + threadIdx.x;
  int n = t >> 4; if (n >= NN) return;
  int g = t & 15;
  int o0 = off[n], o1p = off[n+1];
  int deg = cnt[n];
  int oend = o0 + deg;
  float4 e4 = ((const float4*)er)[n];
  float4 m; m.x=m.y=m.z=m.w=-1e30f;
  for (int c = o0 + g; c < oend; c += 16){
    float4 a = ((const float4*)el)[srcs[c]];
    float4 v;
    v.x=a.x+e4.x; v.x = v.x>=0.f?v.x:0.2f*v.x;
    v.y=a.y+e4.y; v.y = v.y>=0.f?v.y:0.2f*v.y;
    v.z=a.z+e4.z; v.z = v.z>=0.f?v.z:0.2f*v.z;
    v.w=a.w+e4.w; v.w = v.w>=0.f?v.w:0.2f*v.w;
    ((float4*)es)[c]=v;
    m.x=fmaxf(m.x,v.x); m.y=fmaxf(m.y,v.y); m.z=fmaxf(m.z,v.z); m.w=fmaxf(m.w,v.w);
  }
  // zero the pad slots (at most 7)
  { int cp = oend + g; if (cp < o1p){ float4 z; z.x=z.y=z.z=z.w=0.f; ((float4*)es)[cp]=z; } }
  #pragma unroll
  for (int msk = 8; msk >= 1; msk >>= 1){
    m.x=fmaxf(m.x,__shfl_xor(m.x,msk,64)); m.y=fmaxf(m.y,__shfl_xor(m.y,msk,64));
    m.z=fmaxf(m.z,__shfl_xor(m.z,msk,64)); m.w=fmaxf(m.w,__shfl_xor(m.w,msk,64));
  }
  float4 s; s.x=s.y=s.z=s.w=0.f;
  for (int c = o0 + g; c < oend; c += 16){
    float4 v = ((const float4*)es)[c];
    v.x=__expf(v.x-m.x); v.y=__expf(v.y-m.y); v.z=__expf(v.z-m.z); v.w=__expf(v.w-m.w);
    ((float4*)es)[c]=v; s.x+=v.x; s.y+=v.y; s.z+=v.z; s.w+=v.w;
  }
  #pragma unroll
  for (int msk = 8; msk >= 1; msk >>= 1){
    s.x+=__shfl_xor(s.x,msk,64); s.y+=__shfl_xor(s.y,msk,64);
    s.z+=__shfl_xor(s.z,msk,64); s.w+=__shfl_xor(s.w,msk,64);
  }
  if (g == 0){
    float4 r;
    r.x = s.x>0.f ? 1.f/s.x : 0.f;
    r.y = s.y>0.f ? 1.f/s.y : 0.f;
    r.z = s.z>0.f ? 1.f/s.z : 0.f;
    r.w = s.w>0.f ? 1.f/s.w : 0.f;
    ((float4*)recs)[n] = r;
  }
}

// ---------- aggregation for D=64 layers: wave per node, half-wave edge pairs, 16B loads ----------
// padded CSR: no tail, no masking
template<bool RES>
__global__ __launch_bounds__(256) void k_agg64(const u16* __restrict__ feat, const float* __restrict__ es,
    const float* __restrict__ recs, const int* __restrict__ off, const int* __restrict__ srcs,
    const u16* __restrict__ resid, float* __restrict__ outf, u16* __restrict__ outb){
  const int l = threadIdx.x & 63, w = threadIdx.x >> 6;
  const int n = blockIdx.x*4 + w;
  const int o0 = off[n], o1p = off[n+1];
  const int lh = l & 31;
  const int half = l >> 5;
  const int h = lh >> 3;
  float a0=0.f,a1=0.f,a2=0.f,a3=0.f,a4=0.f,a5=0.f,a6=0.f,a7=0.f;
  for (int i = o0; i < o1p; i += 8){
    #pragma unroll
    for (int u=0; u<4; ++u){
      int e = i + u*2 + half;
      int sv = srcs[e];
      float al = es[(size_t)e*4 + h];
      short8 f = *(const short8*)(feat + (size_t)sv*256 + lh*8);
      a0 += al*b2f((u16)f[0]); a1 += al*b2f((u16)f[1]);
      a2 += al*b2f((u16)f[2]); a3 += al*b2f((u16)f[3]);
      a4 += al*b2f((u16)f[4]); a5 += al*b2f((u16)f[5]);
      a6 += al*b2f((u16)f[6]); a7 += al*b2f((u16)f[7]);
    }
  }
  a0 += __shfl_xor(a0,32,64); a1 += __shfl_xor(a1,32,64);
  a2 += __shfl_xor(a2,32,64); a3 += __shfl_xor(a3,32,64);
  a4 += __shfl_xor(a4,32,64); a5 += __shfl_xor(a5,32,64);
  a6 += __shfl_xor(a6,32,64); a7 += __shfl_xor(a7,32,64);
  if (half == 0){
    float rc = recs[n*4+h];
    float v[8] = {a0*rc,a1*rc,a2*rc,a3*rc,a4*rc,a5*rc,a6*rc,a7*rc};
    if (RES){
      short8 r8 = *(const short8*)(resid + (size_t)n*256 + lh*8);
      #pragma unroll
      for (int j=0;j<8;++j) v[j] += b2f((u16)r8[j]);
    }
    #pragma unroll
    for (int j=0;j<8;++j) v[j] = v[j] > 0.f ? v[j] : expm1f(v[j]);
    if (outf){
      float4 q0; q0.x=v[0]; q0.y=v[1]; q0.z=v[2]; q0.w=v[3];
      float4 q1; q1.x=v[4]; q1.y=v[5]; q1.z=v[6]; q1.w=v[7];
      *(float4*)(outf + (size_t)n*256 + lh*8)     = q0;
      *(float4*)(outf + (size_t)n*256 + lh*8 + 4) = q1;
    }
    short8 ob;
    #pragma unroll
    for (int j=0;j<8;++j) ob[j] = (short)f2b(v[j]);
    *(short8*)(outb + (size_t)n*256 + lh*8) = ob;
  }
}

// ---------- output-layer aggregation: 8-edge groups, ushort8 (16B) loads, padded CSR ----------
__global__ __launch_bounds__(256) void k_agg_out(const u16* __restrict__ feat, const float* __restrict__ es,
    const float* __restrict__ recs, const int* __restrict__ off, const int* __restrict__ srcs,
    const u16* __restrict__ reso, float* __restrict__ logits){
  __shared__ float red[4][8][20][8];   // 20480 B
  __shared__ float fin[4][160];        // 2560 B
  const int l = threadIdx.x & 63, w = threadIdx.x >> 6;
  const int n = blockIdx.x*4 + w;
  const int o0 = off[n], o1p = off[n+1];
  // slots: 8 edges x 20 ushort8 blocks = 160; r=0,1 full wave, r=2 lanes<32
  const int s0 = l/20,        q0 = l%20;
  const int s1 = (64+l)/20,   q1 = (64+l)%20;
  const int s2 = (128+l)/20,  q2 = (128+l)%20;   // active l<32
  const int h0 = q0/5, h1 = q1/5, h2 = q2/5;
  float acc0[8], acc1[8], acc2[8];
  #pragma unroll
  for (int j=0;j<8;++j){ acc0[j]=0.f; acc1[j]=0.f; acc2[j]=0.f; }
  for (int i0 = o0; i0 < o1p; i0 += 8){
    {
      int e = i0 + s0; int sv = srcs[e]; float al = es[(size_t)e*4 + h0];
      short8 f = *(const short8*)(feat + (size_t)sv*160 + q0*8);
      #pragma unroll
      for (int j=0;j<8;++j) acc0[j] += al*b2f((u16)f[j]);
    }
    {
      int e = i0 + s1; int sv = srcs[e]; float al = es[(size_t)e*4 + h1];
      short8 f = *(const short8*)(feat + (size_t)sv*160 + q1*8);
      #pragma unroll
      for (int j=0;j<8;++j) acc1[j] += al*b2f((u16)f[j]);
    }
    if (l < 32){
      int e = i0 + s2; int sv = srcs[e]; float al = es[(size_t)e*4 + h2];
      short8 f = *(const short8*)(feat + (size_t)sv*160 + q2*8);
      #pragma unroll
      for (int j=0;j<8;++j) acc2[j] += al*b2f((u16)f[j]);
    }
  }
  #pragma unroll
  for (int j=0;j<8;++j) red[w][s0][q0][j] = acc0[j];
  #pragma unroll
  for (int j=0;j<8;++j) red[w][s1][q1][j] = acc1[j];
  if (l < 32){
    #pragma unroll
    for (int j=0;j<8;++j) red[w][s2][q2][j] = acc2[j];
  }
  __syncthreads();
  if (l < 20){
    const int q = l;
    float rc = recs[n*4 + q/5];
    short8 rr = *(const short8*)(reso + (size_t)n*160 + q*8);
    #pragma unroll
    for (int j=0;j<8;++j){
      float v = red[w][0][q][j];
      #pragma unroll
      for (int s=1;s<8;++s) v += red[w][s][q][j];
      fin[w][q*8+j] = v*rc + b2f((u16)rr[j]);
    }
  }
  __syncthreads();
  if (l < 40) logits[(size_t)n*40 + l] = 0.25f*(fin[w][l]+fin[w][l+40]+fin[w][l+80]+fin[w][l+120]);
}

extern "C" void kernel_launch(void* const* d_in, const int* in_sizes, int n_in,
                              void* d_out, int out_size, void* d_ws, size_t ws_size,
                              hipStream_t stream){
  const float* inputs = (const float*)d_in[0];
  const int*   src    = (const int*)d_in[1];
  const int*   dst    = (const int*)d_in[2];
  const float* W0  = (const float*)d_in[3];
  const float* al0 = (const float*)d_in[4];
  const float* ar0 = (const float*)d_in[5];
  const float* W1  = (const float*)d_in[6];
  const float* al1 = (const float*)d_in[7];
  const float* ar1 = (const float*)d_in[8];
  const float* Wo  = (const float*)d_in[9];
  const float* alo = (const float*)d_in[10];
  const float* aro = (const float*)d_in[11];
  const float* rWo = (const float*)d_in[12];
  const float* fcW = (const float*)d_in[13];

  float* out = (float*)d_out;
  float* out_logits = out;                 // [50000,40]
  float* out_h      = out + 2000000;       // [50000,256]
  float* out_seq    = out + 14800000;      // [50000,64]

  char* ws = (char*)d_ws;
  size_t o = 0;
  auto alc = [&](size_t bytes){ size_t r = o; o += (bytes + 255) & ~(size_t)255; return r; };
  size_t oXb   = alc((size_t)NN*256*2);
  size_t oFA   = alc((size_t)NN*256*2);
  size_t oFB   = alc((size_t)NN*256*2);
  size_t oEs   = alc((size_t)EPAD*4*4);
  size_t oSrcs = alc((size_t)EPAD*4);
  size_t oOff  = alc((size_t)(NN+1)*4);
  size_t oCnt  = alc((size_t)(NN+1)*4);
  size_t oCur  = alc((size_t)NN*4);
  size_t oPart = alc(64*4);
  size_t oEl   = alc((size_t)NN*4*4);
  size_t oEr   = alc((size_t)NN*4*4);
  size_t oRecs = alc((size_t)NN*4*4);
  size_t oReso = alc((size_t)NN*160*2);
  size_t oW0b  = alc(256*256*2);
  size_t oW1b  = alc(256*256*2);
  size_t oWcat = alc(256*320*2);
  size_t oFcb  = alc(256*64*2);
  if (ws_size < o) return;

  u16* Xb   = (u16*)(ws + oXb);
  u16* fA   = (u16*)(ws + oFA);
  u16* fB   = (u16*)(ws + oFB);
  float* es = (float*)(ws + oEs);
  int* srcs = (int*)(ws + oSrcs);
  int* off  = (int*)(ws + oOff);
  int* cnt  = (int*)(ws + oCnt);
  int* cur  = (int*)(ws + oCur);
  int* part = (int*)(ws + oPart);
  float* el = (float*)(ws + oEl);
  float* er = (float*)(ws + oEr);
  float* recs = (float*)(ws + oRecs);
  u16* reso = (u16*)(ws + oReso);
  u16* W0b  = (u16*)(ws + oW0b);
  u16* W1b  = (u16*)(ws + oW1b);
  u16* Wcat = (u16*)(ws + oWcat);
  u16* fcb  = (u16*)(ws + oFcb);

  // ---- converts ----
  k_f2b4<<<(NN*256/4 + 255)/256, 256, 0, stream>>>(inputs, Xb, NN*256/4);
  k_wcvt<<<(36864 + 255)/256, 256, 0, stream>>>(W0, W1, fcW, W0b, W1b, fcb);
  k_catWo<<<(256*320 + 255)/256, 256, 0, stream>>>(rWo, Wo, Wcat);

  // ---- CSR (padded) ----
  hipMemsetAsync(cnt, 0, (size_t)(NN+1)*4, stream);
  hipMemsetAsync(srcs, 0, (size_t)EPAD*4, stream);
  k_count<<<(EE+255)/256, 256, 0, stream>>>(dst, cnt);
  const int NP1 = NN+1, NB = (NP1 + 1023)/1024;
  k_scan_blocks<<<NB, 256, 0, stream>>>(cnt, off, part, NP1);
  k_scan_part<<<1, 64, 0, stream>>>(part, NB);
  k_addback<<<NB, 256, 0, stream>>>(off, cur, part, NP1);
  k_scatter<<<(EE+255)/256, 256, 0, stream>>>(src, dst, cur, srcs);

  dim3 gN256((NN+255)/256, 4), gN320((NN+255)/256, 5), gN64((NN+255)/256, 1);

  // ---- seq_fts = X @ fc_W (f32 out) ----
  k_gemm<0><<<gN64, 256, 0, stream>>>(Xb, fcb, out_seq, nullptr, NN, 64);

  // ---- layer 0 ----
  k_gemm<1><<<gN256, 256, 0, stream>>>(Xb, W0b, fA, nullptr, NN, 256);
  k_eler256<<<(NN*64 + 255)/256, 256, 0, stream>>>(fA, al0, ar0, el, er);
  k_soft<<<(NN*16 + 255)/256, 256, 0, stream>>>(el, er, srcs, off, cnt, es, recs);
  k_agg64<false><<<NN/4, 256, 0, stream>>>(fA, es, recs, off, srcs, nullptr, nullptr, fB);

  // ---- layer 1 ----
  k_gemm<1><<<gN256, 256, 0, stream>>>(fB, W1b, fA, nullptr, NN, 256);
  k_eler256<<<(NN*64 + 255)/256, 256, 0, stream>>>(fA, al1, ar1, el, er);
  k_soft<<<(NN*16 + 255)/256, 256, 0, stream>>>(el, er, srcs, off, cnt, es, recs);
  k_agg64<true><<<NN/4, 256, 0, stream>>>(fA, es, recs, off, srcs, fB, out_h, fB);

  // ---- output layer: fused [reso | feat] GEMM ----
  k_gemm<2><<<gN320, 256, 0, stream>>>(fB, Wcat, reso, fA, NN, 320);
  k_eler<<<(NN*64 + 255)/256, 256, 0, stream>>>(fA, alo, aro, el, er, 40, 160);
  k_soft<<<(NN*16 + 255)/256, 256, 0, stream>>>(el, er, srcs, off, cnt, es, recs);
  k_agg_out<<<NN/4, 256, 0, stream>>>(fA, es, recs, off, srcs, reso, out_logits);
}

// Round 5
// 489.669 us; speedup vs baseline: 1.1985x; 1.0353x over previous
//
#include <hip/hip_runtime.h>

typedef unsigned short u16;
typedef unsigned int u32;
typedef __attribute__((ext_vector_type(8))) short short8;
typedef __attribute__((ext_vector_type(4))) float f32x4;

#define NN 50000
#define EE 800000
#define EPAD (EE + 8*NN)   // max padded edges = 1,200,000

__device__ __forceinline__ float b2f(u16 u){ union{float f;u32 i;}x; x.i=((u32)u)<<16; return x.f; }
__device__ __forceinline__ u16 f2b(float f){ union{float f;u32 i;}x; x.f=f; u32 i=x.i; return (u16)((i + 0x7fffu + ((i>>16)&1u))>>16); }

// ---------- converts ----------
__global__ void k_f2b4(const float* __restrict__ x, u16* __restrict__ y, int n4){
  int i = blockIdx.x*256 + threadIdx.x;
  if (i >= n4) return;
  float4 v = ((const float4*)x)[i];
  ushort4 o; o.x=f2b(v.x); o.y=f2b(v.y); o.z=f2b(v.z); o.w=f2b(v.w);
  ((ushort4*)y)[i]=o;
}

// transpose-convert: W[k=256][N] f32 -> Wt[N][256] bf16
__global__ void k_wtr(const float* __restrict__ W, u16* __restrict__ Wt, int N){
  int i = blockIdx.x*256 + threadIdx.x;
  if (i >= 256*N) return;
  int k = i / N, n = i % N;
  Wt[(size_t)n*256 + k] = f2b(W[i]);
}

// concat-transpose: [rWo | Wo] (each [256][160]) -> Wcat_t[320][256] bf16
__global__ void k_catWoT(const float* __restrict__ rWo, const float* __restrict__ Wo, u16* __restrict__ Bct){
  int i = blockIdx.x*256 + threadIdx.x;
  if (i >= 256*320) return;
  int k = i/320, c = i%320;
  float v = (c < 160) ? rWo[k*160 + c] : Wo[k*160 + (c-160)];
  Bct[(size_t)c*256 + k] = f2b(v);
}

// ---------- CSR build (padded: each node segment rounded up to multiple of 8) ----------
__global__ void k_count(const int* __restrict__ dst, int* __restrict__ cnt){
  int i = blockIdx.x*256+threadIdx.x; if (i<EE) atomicAdd(&cnt[dst[i]],1);
}

__global__ void k_scan_blocks(const int* __restrict__ cnt, int* __restrict__ off, int* __restrict__ part, int n){
  __shared__ int ts[256];
  int t = threadIdx.x; int base = blockIdx.x*1024 + t*4;
  int c0 = (base+0<n)?((cnt[base+0]+7)&~7):0;
  int c1 = (base+1<n)?((cnt[base+1]+7)&~7):0;
  int c2 = (base+2<n)?((cnt[base+2]+7)&~7):0;
  int c3 = (base+3<n)?((cnt[base+3]+7)&~7):0;
  int s = c0+c1+c2+c3;
  ts[t]=s; __syncthreads();
  for (int d=1; d<256; d<<=1){ int v=(t>=d)?ts[t-d]:0; __syncthreads(); ts[t]+=v; __syncthreads(); }
  int ex = ts[t]-s;
  if (t==255) part[blockIdx.x]=ts[255];
  if (base+0<n) off[base+0]=ex; ex+=c0;
  if (base+1<n) off[base+1]=ex; ex+=c1;
  if (base+2<n) off[base+2]=ex; ex+=c2;
  if (base+3<n) off[base+3]=ex;
}

__global__ void k_scan_part(int* part, int nb){
  if (threadIdx.x==0 && blockIdx.x==0){ int run=0; for(int i=0;i<nb;++i){ int v=part[i]; part[i]=run; run+=v; } }
}

// addback and also initialize cur = off
__global__ void k_addback(int* off, int* cur, const int* __restrict__ part, int n){
  int base = blockIdx.x*1024 + threadIdx.x*4; int p = part[blockIdx.x];
  #pragma unroll
  for (int j=0;j<4;++j) if (base+j<n){ int v = off[base+j]+p; off[base+j]=v; if (base+j<NN) cur[base+j]=v; }
}

__global__ void k_scatter(const int* __restrict__ src, const int* __restrict__ dst, int* __restrict__ cur,
                          int* __restrict__ srcs){
  int i = blockIdx.x*256+threadIdx.x; if (i>=EE) return;
  int d = dst[i]; int p = atomicAdd(&cur[d],1);
  srcs[p]=src[i];
}

// ---------- GEMM2: C[M,:] = A[M,256](bf16) @ Bt[N,256]^T, f32 acc ----------
// BM=128, full-K LDS stage via global_load_lds (pre-swizzled source), 256 thr = 4 waves (2Mx2N)
// MODE 0: f32 out C0(ldC). MODE 1: bf16 out C0(ldC). MODE 2: split: c<160 -> C0[r*160+c], 160<=c<320 -> C1[r*160+c-160]
template<int BN, int MODE>
__global__ __launch_bounds__(256) void k_gemm2(const u16* __restrict__ A, const u16* __restrict__ Bt,
                                               void* __restrict__ C0, void* __restrict__ C1,
                                               int M, int ldC){
  __shared__ u16 lds[(128+BN)*256];
  u16* As = lds;                 // [128][256] row-major, 16B-slot XOR-swizzled per row
  u16* Bs = lds + 128*256;       // [BN][256] same
  const int tid = threadIdx.x;
  const int row0 = blockIdx.x * 128;
  const int n0   = blockIdx.y * BN;
  // stage A: 128 rows x 32 slots(16B)
  #pragma unroll
  for (int it=0; it<16; ++it){
    int slot = it*256 + tid;
    int r = slot >> 5, s = slot & 31;
    int gs = s ^ (r & 7);
    const u16* gp = A + (size_t)(row0 + r)*256 + (gs<<3);
    u16* lp = As + (size_t)(it*256 + (tid & ~63))*8;
    __builtin_amdgcn_global_load_lds((const void*)gp, (void*)lp, 16, 0, 0);
  }
  // stage B: BN rows x 32 slots
  #pragma unroll
  for (int it=0; it<BN/8; ++it){
    int slot = it*256 + tid;
    int r = slot >> 5, s = slot & 31;
    int gs = s ^ (r & 7);
    const u16* gp = Bt + (size_t)(n0 + r)*256 + (gs<<3);
    u16* lp = Bs + (size_t)(it*256 + (tid & ~63))*8;
    __builtin_amdgcn_global_load_lds((const void*)gp, (void*)lp, 16, 0, 0);
  }
  __syncthreads();
  const int wave = tid >> 6, l = tid & 63;
  const int wm = wave >> 1, wn = wave & 1;
  const int lr = l & 15, lq = l >> 4;
  const int NR = BN/32;
  f32x4 acc[4][4];
  #pragma unroll
  for (int mr=0;mr<4;++mr)
    #pragma unroll
    for (int nr=0;nr<NR;++nr) acc[mr][nr]=(f32x4)0.0f;
  #pragma unroll
  for (int kk=0; kk<8; ++kk){
    short8 a[4], b[4];
    #pragma unroll
    for (int mr=0;mr<4;++mr){
      int rloc = wm*64 + mr*16 + lr;
      int byo = rloc*512 + ((kk*64 + lq*16) ^ ((rloc&7)<<4));
      a[mr] = *(const short8*)((const char*)As + byo);
    }
    #pragma unroll
    for (int nr=0;nr<NR;++nr){
      int cloc = wn*(BN/2) + nr*16 + lr;
      int byo = cloc*512 + ((kk*64 + lq*16) ^ ((cloc&7)<<4));
      b[nr] = *(const short8*)((const char*)Bs + byo);
    }
    #pragma unroll
    for (int mr=0;mr<4;++mr)
      #pragma unroll
      for (int nr=0;nr<NR;++nr)
        acc[mr][nr] = __builtin_amdgcn_mfma_f32_16x16x32_bf16(a[mr], b[nr], acc[mr][nr], 0, 0, 0);
  }
  #pragma unroll
  for (int mr=0;mr<4;++mr)
    #pragma unroll
    for (int nr=0;nr<NR;++nr)
      #pragma unroll
      for (int q=0;q<4;++q){
        int r = row0 + wm*64 + mr*16 + lq*4 + q;
        if (r < M){
          int c = n0 + wn*(BN/2) + nr*16 + lr;
          float v = acc[mr][nr][q];
          if constexpr (MODE == 0)      ((float*)C0)[(size_t)r*ldC + c] = v;
          else if constexpr (MODE == 1) ((u16*)C0)[(size_t)r*ldC + c] = f2b(v);
          else {
            if (c < 160)      ((u16*)C0)[(size_t)r*160 + c]       = f2b(v);
            else if (c < 320) ((u16*)C1)[(size_t)r*160 + (c-160)] = f2b(v);
          }
        }
      }
}

// ---------- el/er for HD=256 (Dh=64): wave per node, vectorized ----------
__global__ void k_eler256(const u16* __restrict__ feat, const float* __restrict__ al, const float* __restrict__ ar,
                          float* __restrict__ el, float* __restrict__ er){
  int t = blockIdx.x*256 + threadIdx.x;
  int n = t >> 6, l = t & 63;
  if (n >= NN) return;
  float4 a4 = ((const float4*)al)[l];
  float4 r4 = ((const float4*)ar)[l];
  ushort4 f = *(const ushort4*)(feat + (size_t)n*256 + l*4);
  float f0=b2f(f.x), f1=b2f(f.y), f2=b2f(f.z), f3=b2f(f.w);
  float accl = f0*a4.x + f1*a4.y + f2*a4.z + f3*a4.w;
  float accr = f0*r4.x + f1*r4.y + f2*r4.z + f3*r4.w;
  #pragma unroll
  for (int m = 8; m >= 1; m >>= 1){ accl += __shfl_xor(accl, m, 64); accr += __shfl_xor(accr, m, 64); }
  int h = l >> 4;
  if ((l & 15) == 0){ el[n*4+h] = accl; er[n*4+h] = accr; }
}

// ---------- generic el/er (output layer: Dh=40, HD=160) ----------
__global__ void k_eler(const u16* __restrict__ feat, const float* __restrict__ al, const float* __restrict__ ar,
                       float* __restrict__ el, float* __restrict__ er, int Dh, int HD){
  int t = blockIdx.x*256 + threadIdx.x;
  int n = t >> 6; int l = t & 63;
  if (n >= NN) return;
  int h = l >> 4, s = l & 15;
  const u16* fr = feat + (size_t)n*HD + h*Dh;
  const float* alh = al + h*Dh; const float* arh = ar + h*Dh;
  float accl = 0.f, accr = 0.f;
  for (int d = s; d < Dh; d += 16){ float f = b2f(fr[d]); accl += f*alh[d]; accr += f*arh[d]; }
  #pragma unroll
  for (int m = 8; m >= 1; m >>= 1){ accl += __shfl_xor(accl, m, 64); accr += __shfl_xor(accr, m, 64); }
  if (s == 0){ el[n*4+h] = accl; er[n*4+h] = accr; }
}

// ---------- edge-parallel softmax: 16 lanes per node ----------
__global__ void k_soft(const float* __restrict__ el, const float* __restrict__ er,
                       const int* __restrict__ srcs, const int* __restrict__ off, const int* __restrict__ cnt,
                       float* __restrict__ es, float* __restrict__ recs){
  int t = blockIdx.x*256 + threadIdx.x;
  int n = t >> 4; if (n >= NN) return;
  int g = t & 15;
  int o0 = off[n], o1p = off[n+1];
  int deg = cnt[n];
  int oend = o0 + deg;
  float4 e4 = ((const float4*)er)[n];
  float4 m; m.x=m.y=m.z=m.w=-1e30f;
  for (int c = o0 + g; c < oend; c += 16){
    float4 a = ((const float4*)el)[srcs[c]];
    float4 v;
    v.x=a.x+e4.x; v.x = v.x>=0.f?v.x:0.2f*v.x;
    v.y=a.y+e4.y; v.y = v.y>=0.f?v.y:0.2f*v.y;
    v.z=a.z+e4.z; v.z = v.z>=0.f?v.z:0.2f*v.z;
    v.w=a.w+e4.w; v.w = v.w>=0.f?v.w:0.2f*v.w;
    ((float4*)es)[c]=v;
    m.x=fmaxf(m.x,v.x); m.y=fmaxf(m.y,v.y); m.z=fmaxf(m.z,v.z); m.w=fmaxf(m.w,v.w);
  }
  { int cp = oend + g; if (cp < o1p){ float4 z; z.x=z.y=z.z=z.w=0.f; ((float4*)es)[cp]=z; } }
  #pragma unroll
  for (int msk = 8; msk >= 1; msk >>= 1){
    m.x=fmaxf(m.x,__shfl_xor(m.x,msk,64)); m.y=fmaxf(m.y,__shfl_xor(m.y,msk,64));
    m.z=fmaxf(m.z,__shfl_xor(m.z,msk,64)); m.w=fmaxf(m.w,__shfl_xor(m.w,msk,64));
  }
  float4 s; s.x=s.y=s.z=s.w=0.f;
  for (int c = o0 + g; c < oend; c += 16){
    float4 v = ((const float4*)es)[c];
    v.x=__expf(v.x-m.x); v.y=__expf(v.y-m.y); v.z=__expf(v.z-m.z); v.w=__expf(v.w-m.w);
    ((float4*)es)[c]=v; s.x+=v.x; s.y+=v.y; s.z+=v.z; s.w+=v.w;
  }
  #pragma unroll
  for (int msk = 8; msk >= 1; msk >>= 1){
    s.x+=__shfl_xor(s.x,msk,64); s.y+=__shfl_xor(s.y,msk,64);
    s.z+=__shfl_xor(s.z,msk,64); s.w+=__shfl_xor(s.w,msk,64);
  }
  if (g == 0){
    float4 r;
    r.x = s.x>0.f ? 1.f/s.x : 0.f;
    r.y = s.y>0.f ? 1.f/s.y : 0.f;
    r.z = s.z>0.f ? 1.f/s.z : 0.f;
    r.w = s.w>0.f ? 1.f/s.w : 0.f;
    ((float4*)recs)[n] = r;
  }
}

// ---------- aggregation for D=64 layers: wave per node, half-wave edge pairs, 16-deep unroll ----------
template<bool RES>
__global__ __launch_bounds__(256) void k_agg64(const u16* __restrict__ feat, const float* __restrict__ es,
    const float* __restrict__ recs, const int* __restrict__ off, const int* __restrict__ srcs,
    const u16* __restrict__ resid, float* __restrict__ outf, u16* __restrict__ outb){
  const int l = threadIdx.x & 63, w = threadIdx.x >> 6;
  const int n = blockIdx.x*4 + w;
  const int o0 = off[n], o1p = off[n+1];
  const int lh = l & 31;
  const int half = l >> 5;
  const int h = lh >> 3;
  float a0=0.f,a1=0.f,a2=0.f,a3=0.f,a4=0.f,a5=0.f,a6=0.f,a7=0.f;
  int i = o0;
  for (; i + 16 <= o1p; i += 16){
    #pragma unroll
    for (int u=0; u<8; ++u){
      int e = i + u*2 + half;
      int sv = srcs[e];
      float al = es[(size_t)e*4 + h];
      short8 f = *(const short8*)(feat + (size_t)sv*256 + lh*8);
      a0 += al*b2f((u16)f[0]); a1 += al*b2f((u16)f[1]);
      a2 += al*b2f((u16)f[2]); a3 += al*b2f((u16)f[3]);
      a4 += al*b2f((u16)f[4]); a5 += al*b2f((u16)f[5]);
      a6 += al*b2f((u16)f[6]); a7 += al*b2f((u16)f[7]);
    }
  }
  if (i < o1p){
    #pragma unroll
    for (int u=0; u<4; ++u){
      int e = i + u*2 + half;
      int sv = srcs[e];
      float al = es[(size_t)e*4 + h];
      short8 f = *(const short8*)(feat + (size_t)sv*256 + lh*8);
      a0 += al*b2f((u16)f[0]); a1 += al*b2f((u16)f[1]);
      a2 += al*b2f((u16)f[2]); a3 += al*b2f((u16)f[3]);
      a4 += al*b2f((u16)f[4]); a5 += al*b2f((u16)f[5]);
      a6 += al*b2f((u16)f[6]); a7 += al*b2f((u16)f[7]);
    }
  }
  a0 += __shfl_xor(a0,32,64); a1 += __shfl_xor(a1,32,64);
  a2 += __shfl_xor(a2,32,64); a3 += __shfl_xor(a3,32,64);
  a4 += __shfl_xor(a4,32,64); a5 += __shfl_xor(a5,32,64);
  a6 += __shfl_xor(a6,32,64); a7 += __shfl_xor(a7,32,64);
  if (half == 0){
    float rc = recs[n*4+h];
    float v[8] = {a0*rc,a1*rc,a2*rc,a3*rc,a4*rc,a5*rc,a6*rc,a7*rc};
    if (RES){
      short8 r8 = *(const short8*)(resid + (size_t)n*256 + lh*8);
      #pragma unroll
      for (int j=0;j<8;++j) v[j] += b2f((u16)r8[j]);
    }
    #pragma unroll
    for (int j=0;j<8;++j) v[j] = v[j] > 0.f ? v[j] : expm1f(v[j]);
    if (outf){
      float4 q0; q0.x=v[0]; q0.y=v[1]; q0.z=v[2]; q0.w=v[3];
      float4 q1; q1.x=v[4]; q1.y=v[5]; q1.z=v[6]; q1.w=v[7];
      *(float4*)(outf + (size_t)n*256 + lh*8)     = q0;
      *(float4*)(outf + (size_t)n*256 + lh*8 + 4) = q1;
    }
    short8 ob;
    #pragma unroll
    for (int j=0;j<8;++j) ob[j] = (short)f2b(v[j]);
    *(short8*)(outb + (size_t)n*256 + lh*8) = ob;
  }
}

// ---------- output-layer aggregation: 8-edge groups, ushort8 (16B) loads, padded CSR ----------
__global__ __launch_bounds__(256) void k_agg_out(const u16* __restrict__ feat, const float* __restrict__ es,
    const float* __restrict__ recs, const int* __restrict__ off, const int* __restrict__ srcs,
    const u16* __restrict__ reso, float* __restrict__ logits){
  __shared__ float red[4][8][20][8];   // 20480 B
  __shared__ float fin[4][160];        // 2560 B
  const int l = threadIdx.x & 63, w = threadIdx.x >> 6;
  const int n = blockIdx.x*4 + w;
  const int o0 = off[n], o1p = off[n+1];
  const int s0 = l/20,        q0 = l%20;
  const int s1 = (64+l)/20,   q1 = (64+l)%20;
  const int s2 = (128+l)/20,  q2 = (128+l)%20;   // active l<32
  const int h0 = q0/5, h1 = q1/5, h2 = q2/5;
  float acc0[8], acc1[8], acc2[8];
  #pragma unroll
  for (int j=0;j<8;++j){ acc0[j]=0.f; acc1[j]=0.f; acc2[j]=0.f; }
  for (int i0 = o0; i0 < o1p; i0 += 8){
    {
      int e = i0 + s0; int sv = srcs[e]; float al = es[(size_t)e*4 + h0];
      short8 f = *(const short8*)(feat + (size_t)sv*160 + q0*8);
      #pragma unroll
      for (int j=0;j<8;++j) acc0[j] += al*b2f((u16)f[j]);
    }
    {
      int e = i0 + s1; int sv = srcs[e]; float al = es[(size_t)e*4 + h1];
      short8 f = *(const short8*)(feat + (size_t)sv*160 + q1*8);
      #pragma unroll
      for (int j=0;j<8;++j) acc1[j] += al*b2f((u16)f[j]);
    }
    if (l < 32){
      int e = i0 + s2; int sv = srcs[e]; float al = es[(size_t)e*4 + h2];
      short8 f = *(const short8*)(feat + (size_t)sv*160 + q2*8);
      #pragma unroll
      for (int j=0;j<8;++j) acc2[j] += al*b2f((u16)f[j]);
    }
  }
  #pragma unroll
  for (int j=0;j<8;++j) red[w][s0][q0][j] = acc0[j];
  #pragma unroll
  for (int j=0;j<8;++j) red[w][s1][q1][j] = acc1[j];
  if (l < 32){
    #pragma unroll
    for (int j=0;j<8;++j) red[w][s2][q2][j] = acc2[j];
  }
  __syncthreads();
  if (l < 20){
    const int q = l;
    float rc = recs[n*4 + q/5];
    short8 rr = *(const short8*)(reso + (size_t)n*160 + q*8);
    #pragma unroll
    for (int j=0;j<8;++j){
      float v = red[w][0][q][j];
      #pragma unroll
      for (int s=1;s<8;++s) v += red[w][s][q][j];
      fin[w][q*8+j] = v*rc + b2f((u16)rr[j]);
    }
  }
  __syncthreads();
  if (l < 40) logits[(size_t)n*40 + l] = 0.25f*(fin[w][l]+fin[w][l+40]+fin[w][l+80]+fin[w][l+120]);
}

extern "C" void kernel_launch(void* const* d_in, const int* in_sizes, int n_in,
                              void* d_out, int out_size, void* d_ws, size_t ws_size,
                              hipStream_t stream){
  const float* inputs = (const float*)d_in[0];
  const int*   src    = (const int*)d_in[1];
  const int*   dst    = (const int*)d_in[2];
  const float* W0  = (const float*)d_in[3];
  const float* al0 = (const float*)d_in[4];
  const float* ar0 = (const float*)d_in[5];
  const float* W1  = (const float*)d_in[6];
  const float* al1 = (const float*)d_in[7];
  const float* ar1 = (const float*)d_in[8];
  const float* Wo  = (const float*)d_in[9];
  const float* alo = (const float*)d_in[10];
  const float* aro = (const float*)d_in[11];
  const float* rWo = (const float*)d_in[12];
  const float* fcW = (const float*)d_in[13];

  float* out = (float*)d_out;
  float* out_logits = out;                 // [50000,40]
  float* out_h      = out + 2000000;       // [50000,256]
  float* out_seq    = out + 14800000;      // [50000,64]

  char* ws = (char*)d_ws;
  size_t o = 0;
  auto alc = [&](size_t bytes){ size_t r = o; o += (bytes + 255) & ~(size_t)255; return r; };
  size_t oXb   = alc((size_t)NN*256*2);
  size_t oFA   = alc((size_t)NN*256*2);
  size_t oFB   = alc((size_t)NN*256*2);
  size_t oEs   = alc((size_t)EPAD*4*4);
  size_t oSrcs = alc((size_t)EPAD*4);
  size_t oOff  = alc((size_t)(NN+1)*4);
  size_t oCnt  = alc((size_t)(NN+1)*4);
  size_t oCur  = alc((size_t)NN*4);
  size_t oPart = alc(64*4);
  size_t oEl   = alc((size_t)NN*4*4);
  size_t oEr   = alc((size_t)NN*4*4);
  size_t oRecs = alc((size_t)NN*4*4);
  size_t oReso = alc((size_t)NN*160*2);
  size_t oW0t  = alc(256*256*2);
  size_t oW1t  = alc(256*256*2);
  size_t oWct  = alc((size_t)384*256*2);   // 320 valid rows + 64 slack for staging overrun
  size_t oFct  = alc((size_t)128*256*2);   // 64 valid rows + slack
  if (ws_size < o) return;

  u16* Xb   = (u16*)(ws + oXb);
  u16* fA   = (u16*)(ws + oFA);
  u16* fB   = (u16*)(ws + oFB);
  float* es = (float*)(ws + oEs);
  int* srcs = (int*)(ws + oSrcs);
  int* off  = (int*)(ws + oOff);
  int* cnt  = (int*)(ws + oCnt);
  int* cur  = (int*)(ws + oCur);
  int* part = (int*)(ws + oPart);
  float* el = (float*)(ws + oEl);
  float* er = (float*)(ws + oEr);
  float* recs = (float*)(ws + oRecs);
  u16* reso = (u16*)(ws + oReso);
  u16* W0t  = (u16*)(ws + oW0t);
  u16* W1t  = (u16*)(ws + oW1t);
  u16* Wct  = (u16*)(ws + oWct);
  u16* fct  = (u16*)(ws + oFct);

  // ---- converts (weights transposed for GEMM2 B-staging) ----
  k_f2b4<<<(NN*256/4 + 255)/256, 256, 0, stream>>>(inputs, Xb, NN*256/4);
  k_wtr<<<(256*256 + 255)/256, 256, 0, stream>>>(W0, W0t, 256);
  k_wtr<<<(256*256 + 255)/256, 256, 0, stream>>>(W1, W1t, 256);
  k_wtr<<<(256*64 + 255)/256, 256, 0, stream>>>(fcW, fct, 64);
  k_catWoT<<<(256*320 + 255)/256, 256, 0, stream>>>(rWo, Wo, Wct);

  // ---- CSR (padded) ----
  hipMemsetAsync(cnt, 0, (size_t)(NN+1)*4, stream);
  hipMemsetAsync(srcs, 0, (size_t)EPAD*4, stream);
  k_count<<<(EE+255)/256, 256, 0, stream>>>(dst, cnt);
  const int NP1 = NN+1, NB = (NP1 + 1023)/1024;
  k_scan_blocks<<<NB, 256, 0, stream>>>(cnt, off, part, NP1);
  k_scan_part<<<1, 64, 0, stream>>>(part, NB);
  k_addback<<<NB, 256, 0, stream>>>(off, cur, part, NP1);
  k_scatter<<<(EE+255)/256, 256, 0, stream>>>(src, dst, cur, srcs);

  const int GX = (NN + 127)/128;   // 391
  dim3 g256(GX, 2), g320(GX, 3), g64(GX, 1);

  // ---- seq_fts = X @ fc_W (f32 out) ----
  k_gemm2<64,0><<<g64, 256, 0, stream>>>(Xb, fct, out_seq, nullptr, NN, 64);

  // ---- layer 0 ----
  k_gemm2<128,1><<<g256, 256, 0, stream>>>(Xb, W0t, fA, nullptr, NN, 256);
  k_eler256<<<(NN*64 + 255)/256, 256, 0, stream>>>(fA, al0, ar0, el, er);
  k_soft<<<(NN*16 + 255)/256, 256, 0, stream>>>(el, er, srcs, off, cnt, es, recs);
  k_agg64<false><<<NN/4, 256, 0, stream>>>(fA, es, recs, off, srcs, nullptr, nullptr, fB);

  // ---- layer 1 ----
  k_gemm2<128,1><<<g256, 256, 0, stream>>>(fB, W1t, fA, nullptr, NN, 256);
  k_eler256<<<(NN*64 + 255)/256, 256, 0, stream>>>(fA, al1, ar1, el, er);
  k_soft<<<(NN*16 + 255)/256, 256, 0, stream>>>(el, er, srcs, off, cnt, es, recs);
  k_agg64<true><<<NN/4, 256, 0, stream>>>(fA, es, recs, off, srcs, fB, out_h, fB);

  // ---- output layer: fused [reso | Wo] GEMM ----
  k_gemm2<128,2><<<g320, 256, 0, stream>>>(fB, Wct, reso, fA, NN, 320);
  k_eler<<<(NN*64 + 255)/256, 256, 0, stream>>>(fA, alo, aro, el, er, 40, 160);
  k_soft<<<(NN*16 + 255)/256, 256, 0, stream>>>(el, er, srcs, off, cnt, es, recs);
  k_agg_out<<<NN/4, 256, 0, stream>>>(fA, es, recs, off, srcs, reso, out_logits);
}